// Round 1
// baseline (159.814 us; speedup 1.0000x reference)
//
#include <hip/hip_runtime.h>

#define N_NODES 50000
#define N_EDGES 800000
#define F 64
#define CHUNK 3072       // edges per partition workgroup (R17: 6144->3072, 262 blocks > 256 CUs)
#define NWG1 ((N_EDGES + CHUNK - 1) / CHUNK)   // 261
#define NBUCK 196        // coarse buckets: dst >> 8
#define BSTRIDE 8192     // fixed per-bucket capacity (mean 4082, sigma ~64)
#define NWTILE (N_NODES / 16)   // 3125 exact

typedef __attribute__((ext_vector_type(8))) _Float16 half8;   // 16 B
typedef __attribute__((ext_vector_type(4))) float f32x4;

// ---------- K1: partition into fixed-capacity buckets + f16 convert + W prep ----
// (R14 proven) Single unified f16 feature table x16 [N,64].
__global__ __launch_bounds__(256) void partition_conv(
    const int*    __restrict__ src, const int* __restrict__ dst,
    const float4* __restrict__ xin,      // [N*16] float4 view of x
    half8*        __restrict__ x16,      // [N*8] f16 rows
    const float*  __restrict__ W1, const float* __restrict__ W2,
    _Float16*     __restrict__ Wt1, _Float16* __restrict__ Wt2,
    unsigned*     __restrict__ bcur,     // [256] zeroed cursors
    unsigned*     __restrict__ ebuf) {   // [NBUCK*BSTRIDE] strided buckets
  int t = threadIdx.x, b = blockIdx.x;
  if (b == NWG1) {                       // W prep block
    for (int i = t; i < 64 * 128; i += 256) {
      int n = i >> 7, k = i & 127;       // Wt[n][k] = W[k][n]
      Wt1[i] = (_Float16)W1[k * 64 + n];
      Wt2[i] = (_Float16)W2[k * 64 + n];
    }
    return;
  }
  __shared__ int hist[256], lscan[256], lcur[256], gbase[256];
  __shared__ unsigned stage[CHUNK];      // 12 KB
  hist[t] = 0; __syncthreads();
  int e0 = b * CHUNK;
  int cnt = N_EDGES - e0; if (cnt > CHUNK) cnt = CHUNK;
  for (int i = t; i < cnt; i += 256) atomicAdd(&hist[dst[e0 + i] >> 8], 1);

  // f32 -> f16 feature conversion, grid-stride
  const int TOT = N_NODES * F / 8;
  for (int i = b * 256 + t; i < TOT; i += NWG1 * 256) {
    float4 a = xin[i * 2], c = xin[i * 2 + 1];
    half8 hh;
    hh[0] = (_Float16)a.x; hh[1] = (_Float16)a.y;
    hh[2] = (_Float16)a.z; hh[3] = (_Float16)a.w;
    hh[4] = (_Float16)c.x; hh[5] = (_Float16)c.y;
    hh[6] = (_Float16)c.z; hh[7] = (_Float16)c.w;
    x16[i] = hh;
  }
  __syncthreads();

  int v = hist[t];
  lscan[t] = v; __syncthreads();
  for (int off = 1; off < 256; off <<= 1) {
    int a = (t >= off) ? lscan[t - off] : 0;
    __syncthreads();
    lscan[t] += a;
    __syncthreads();
  }
  lscan[t] -= v;                         // exclusive local scan
  lcur[t] = lscan[t];
  if (v > 0) gbase[t] = (int)atomicAdd(&bcur[t], (unsigned)v);  // in-bucket base
  __syncthreads();

  for (int i = t; i < cnt; i += 256) {
    int d = dst[e0 + i], s = src[e0 + i];
    int bb = d >> 8;
    int p = atomicAdd(&lcur[bb], 1);
    stage[p] = ((unsigned)bb << 24) | ((unsigned)(d & 255) << 16) | (unsigned)s;
  }
  __syncthreads();
  for (int i = t; i < cnt; i += 256) {
    unsigned e = stage[i];
    int bb = e >> 24;
    ebuf[bb * BSTRIDE + gbase[bb] + (i - lscan[bb])] = e;   // coalesced runs
  }
}

// ---------- K2: per-bucket counting sort, split by key half-range ----------
// (R17) Each bucket handled by TWO blocks: block B -> bucket B>>1, half B&1
// (bins h*128 .. h*128+127). Each block histograms/scans only its own 128
// bins; its output base is h ? cnt - total_own : 0 (no cross-block comm).
// Per-block LDS-atomic work ~55% of the unsplit version, grid 196 -> 392.
__global__ __launch_bounds__(256) void bucket_sort(
    const unsigned* __restrict__ ebuf, const unsigned* __restrict__ bcur,
    unsigned short* __restrict__ edge_src, int* __restrict__ row_start,
    int* __restrict__ deg) {
  __shared__ int lhist[128], lscan[128], lcur[128];
  __shared__ unsigned short srt[BSTRIDE / 2];    // 8 KB (half ~2048 +- 45)
  int B = blockIdx.x, t = threadIdx.x;
  int b = B >> 1, h = B & 1;
  int s0 = b * BSTRIDE;
  int cnt = (int)bcur[b];

  if (t < 128) lhist[t] = 0;
  __syncthreads();
  for (int i = t; i < cnt; i += 256) {
    int bin = (int)((ebuf[s0 + i] >> 16) & 255);
    if ((bin >> 7) == h) atomicAdd(&lhist[bin & 127], 1);
  }
  __syncthreads();

  int v = (t < 128) ? lhist[t] : 0;
  if (t < 128) lscan[t] = v;
  __syncthreads();
  for (int off = 1; off < 128; off <<= 1) {
    int a = (t >= off && t < 128) ? lscan[t - off] : 0;
    __syncthreads();
    if (t < 128) lscan[t] += a;
    __syncthreads();
  }
  if (t < 128) { lscan[t] -= v; lcur[t] = lscan[t]; }   // exclusive scan
  __syncthreads();

  int total = lscan[127] + lhist[127];   // edges in this half
  int base  = h ? (cnt - total) : 0;     // offset of this half within bucket

  for (int i = t; i < cnt; i += 256) {
    unsigned e = ebuf[s0 + i];
    int bin = (int)((e >> 16) & 255);
    if ((bin >> 7) == h) {
      int p = atomicAdd(&lcur[bin & 127], 1);
      srt[p] = (unsigned short)(e & 0xFFFFu);
    }
  }
  __syncthreads();

  for (int i = t; i < total; i += 256) edge_src[s0 + base + i] = srt[i];  // coalesced 2B

  if (t < 128) {
    int n = b * 256 + h * 128 + t;
    if (n < N_NODES) { row_start[n] = s0 + base + lscan[t]; deg[n] = v; }
  }
}

// ---------- fused layer: octet-per-node aggregate -> LDS -> MFMA linear ----------
// (R13/R14 proven structure) Block = 4 waves = 32 nodes = 2 MFMA tiles.
// Phase 1: octet o owns node blk*32+w*8+o; lane q holds feature octet q (16 B);
//   single pass, 8 gathers in flight; PACKED f16 accumulation (half8 += half8 ->
//   4x v_pk_add_f16, accuracy HW-validated in R16: absmax identical to f32 accum).
// Phase 2: MFMA linear; wave w does nt-half (w&1) of tile (w>>1).
__global__ __launch_bounds__(256) void sage_layer_fused(
    const half8*    __restrict__ feat16,    // [N,8] gather source (= self16)
    const _Float16* __restrict__ self16,    // [N,64]
    const int*      __restrict__ row_start,
    const int*      __restrict__ deg,
    const unsigned short* __restrict__ edge_src,
    const _Float16* __restrict__ Wt,        // [64,128]  Wt[n][k] = W[k][n]
    const float*    __restrict__ bias,      // [64]
    float*          __restrict__ outf,      // [N,64] f32 or null
    unsigned short* __restrict__ out16,     // [N,64] f16 or null
    int do_relu) {
  __shared__ _Float16 lmean[32 * 72];       // node stride 72 halves, 4.6 KB
  int t = threadIdx.x;
  int w = t >> 6, lane = t & 63;

  // ---- phase 1: aggregate 8 nodes per wave (octet-per-node, packed f16) ----
  {
    int o = lane >> 3, q = lane & 7;
    int n = blockIdx.x * 32 + w * 8 + o;
    if (n < N_NODES) {
      int start = row_start[n];
      int d     = deg[n];
      half8 acc8 = (half8){0, 0, 0, 0, 0, 0, 0, 0};
      for (int base = 0; base < d; base += 8) {
        #pragma unroll
        for (int uu = 0; uu < 8; ++uu) {
          int e = base + uu;
          if (e < d) {
            int s = (int)edge_src[start + e];        // broadcast within octet
            acc8 += feat16[(size_t)s * 8 + q];       // 128 B row; v_pk_add_f16
          }
        }
      }
      float inv = (d > 0) ? 1.0f / (float)d : 0.0f;
      half8 h;
      #pragma unroll
      for (int k = 0; k < 8; ++k) h[k] = (_Float16)((float)acc8[k] * inv);
      *(half8*)&lmean[(w * 8 + o) * 72 + q * 8] = h;
    }
  }
  __syncthreads();

  // ---- phase 2: MFMA linear; wave w does nt-half (w&1) of tile (w>>1) ----
  int tile = w >> 1;
  int wt = blockIdx.x * 2 + tile;
  if (wt >= NWTILE) return;
  int m = lane & 15, quad = lane >> 4;
  size_t arow = (size_t)(wt * 16 + m) * 64 + quad * 8;
  half8 a0 = *(const half8*)(self16 + arow);
  half8 a1 = *(const half8*)(self16 + arow + 32);
  int ln = tile * 16 + m;                   // local node 0..31
  half8 a2 = *(const half8*)&lmean[ln * 72 + quad * 8];
  half8 a3 = *(const half8*)&lmean[ln * 72 + quad * 8 + 32];

  int nt0 = (w & 1) * 2;                    // 0 or 2
  #pragma unroll
  for (int i = 0; i < 2; ++i) {
    int nt = nt0 + i;
    float bv = bias[nt * 16 + m];           // col = lane&15
    f32x4 acc = (f32x4){bv, bv, bv, bv};
    const _Float16* wrow = Wt + (size_t)(nt * 16 + m) * 128 + quad * 8;
    half8 b0 = *(const half8*)(wrow);
    half8 b1 = *(const half8*)(wrow + 32);
    half8 b2 = *(const half8*)(wrow + 64);
    half8 b3 = *(const half8*)(wrow + 96);
    acc = __builtin_amdgcn_mfma_f32_16x16x32_f16(a0, b0, acc, 0, 0, 0);
    acc = __builtin_amdgcn_mfma_f32_16x16x32_f16(a1, b1, acc, 0, 0, 0);
    acc = __builtin_amdgcn_mfma_f32_16x16x32_f16(a2, b2, acc, 0, 0, 0);
    acc = __builtin_amdgcn_mfma_f32_16x16x32_f16(a3, b3, acc, 0, 0, 0);
    #pragma unroll
    for (int r = 0; r < 4; ++r) {
      size_t off = (size_t)(wt * 16 + quad * 4 + r) * 64 + nt * 16 + m;
      float v = acc[r];
      if (do_relu) v = fmaxf(v, 0.0f);
      if (outf)  outf[off] = v;
      if (out16) { _Float16 hv = (_Float16)v; out16[off] = *(unsigned short*)&hv; }
    }
  }
}

extern "C" void kernel_launch(void* const* d_in, const int* in_sizes, int n_in,
                              void* d_out, int out_size, void* d_ws, size_t ws_size,
                              hipStream_t stream) {
  const float* x  = (const float*)d_in[0];
  const int*   ei = (const int*)d_in[1];   // [2,E]: row 0 = src, row 1 = dst
  const float* W1 = (const float*)d_in[2];
  const float* b1 = (const float*)d_in[3];
  const float* W2 = (const float*)d_in[4];
  const float* b2 = (const float*)d_in[5];
  float* out = (float*)d_out;

  const int* src = ei;
  const int* dst = ei + N_EDGES;

  // ws layout (int offsets), all 16B-aligned (R14 proven):
  //   bcur@0[256] | deg@256[50048] | row_start@50304[50048] |
  //   edge_src@100352[196*8192 ushorts = 802816 ints] | ebuf@903168[1605632] |
  //   x16@2508800[1600000] | h116@4108800[1600000] |
  //   Wt1@5708800[4096] | Wt2@5712896[4096]   total 5,716,992 ints = 22.9 MB
  int* wsi       = (int*)d_ws;
  unsigned* bcur = (unsigned*)wsi;
  int* deg       = wsi + 256;
  int* row_start = wsi + 50304;
  unsigned short* edge_src = (unsigned short*)(wsi + 100352);
  unsigned* ebuf = (unsigned*)(wsi + 903168);
  half8* x16     = (half8*)(wsi + 2508800);
  unsigned short* h116 = (unsigned short*)(wsi + 4108800);
  _Float16* Wt1  = (_Float16*)(wsi + 5708800);
  _Float16* Wt2  = (_Float16*)(wsi + 5712896);

  hipMemsetAsync(bcur, 0, 256 * sizeof(unsigned), stream);

  dim3 blk(256);
  partition_conv<<<NWG1 + 1, blk, 0, stream>>>(
      src, dst, (const float4*)x, x16, W1, W2, Wt1, Wt2, bcur, ebuf);
  bucket_sort<<<NBUCK * 2, blk, 0, stream>>>(ebuf, bcur, edge_src, row_start, deg);

  dim3 grd_fused((N_NODES + 31) / 32);   // 1563 blocks = 3126 tiles >= 3125

  // Layer 1: h1 = relu([x||mean]W1+b1), kept only as f16
  sage_layer_fused<<<grd_fused, blk, 0, stream>>>(
      x16, (const _Float16*)x16, row_start, deg, edge_src,
      Wt1, b1, nullptr, h116, 1);
  // Layer 2: out = [h1||mean]W2+b2 (f32)
  sage_layer_fused<<<grd_fused, blk, 0, stream>>>(
      (const half8*)h116, (const _Float16*)h116, row_start, deg, edge_src,
      Wt2, b2, out, nullptr, 0);
}

// Round 2
// 147.467 us; speedup vs baseline: 1.0837x; 1.0837x over previous
//
#include <hip/hip_runtime.h>

#define N_NODES 50000
#define N_EDGES 800000
#define F 64
#define CHUNK 3072       // edges per partition workgroup (R17: 262 blocks > 256 CUs)
#define NWG1 ((N_EDGES + CHUNK - 1) / CHUNK)   // 261
#define NBUCK 196        // coarse buckets: dst >> 8
#define BSTRIDE 8192     // fixed per-bucket capacity (mean 4082, sigma ~64)
#define NWTILE (N_NODES / 16)   // 3125 exact

typedef __attribute__((ext_vector_type(8))) _Float16 half8;   // 16 B
typedef __attribute__((ext_vector_type(4))) float f32x4;

// ---------- K1: partition into fixed-capacity buckets + f16 convert + W prep ----
__global__ __launch_bounds__(256) void partition_conv(
    const int*    __restrict__ src, const int* __restrict__ dst,
    const float4* __restrict__ xin,      // [N*16] float4 view of x
    half8*        __restrict__ x16,      // [N*8] f16 rows
    const float*  __restrict__ W1, const float* __restrict__ W2,
    _Float16*     __restrict__ Wt1, _Float16* __restrict__ Wt2,
    unsigned*     __restrict__ bcur,     // [256] zeroed cursors
    unsigned*     __restrict__ ebuf) {   // [NBUCK*BSTRIDE] strided buckets
  int t = threadIdx.x, b = blockIdx.x;
  if (b == NWG1) {                       // W prep block
    for (int i = t; i < 64 * 128; i += 256) {
      int n = i >> 7, k = i & 127;       // Wt[n][k] = W[k][n]
      Wt1[i] = (_Float16)W1[k * 64 + n];
      Wt2[i] = (_Float16)W2[k * 64 + n];
    }
    return;
  }
  __shared__ int hist[256], lscan[256], lcur[256], gbase[256];
  __shared__ unsigned stage[CHUNK];      // 12 KB
  hist[t] = 0; __syncthreads();
  int e0 = b * CHUNK;
  int cnt = N_EDGES - e0; if (cnt > CHUNK) cnt = CHUNK;
  for (int i = t; i < cnt; i += 256) atomicAdd(&hist[dst[e0 + i] >> 8], 1);

  // f32 -> f16 feature conversion, grid-stride
  const int TOT = N_NODES * F / 8;
  for (int i = b * 256 + t; i < TOT; i += NWG1 * 256) {
    float4 a = xin[i * 2], c = xin[i * 2 + 1];
    half8 hh;
    hh[0] = (_Float16)a.x; hh[1] = (_Float16)a.y;
    hh[2] = (_Float16)a.z; hh[3] = (_Float16)a.w;
    hh[4] = (_Float16)c.x; hh[5] = (_Float16)c.y;
    hh[6] = (_Float16)c.z; hh[7] = (_Float16)c.w;
    x16[i] = hh;
  }
  __syncthreads();

  int v = hist[t];
  lscan[t] = v; __syncthreads();
  for (int off = 1; off < 256; off <<= 1) {
    int a = (t >= off) ? lscan[t - off] : 0;
    __syncthreads();
    lscan[t] += a;
    __syncthreads();
  }
  lscan[t] -= v;                         // exclusive local scan
  lcur[t] = lscan[t];
  if (v > 0) gbase[t] = (int)atomicAdd(&bcur[t], (unsigned)v);  // in-bucket base
  __syncthreads();

  for (int i = t; i < cnt; i += 256) {
    int d = dst[e0 + i], s = src[e0 + i];
    int bb = d >> 8;
    int p = atomicAdd(&lcur[bb], 1);
    stage[p] = ((unsigned)bb << 24) | ((unsigned)(d & 255) << 16) | (unsigned)s;
  }
  __syncthreads();
  for (int i = t; i < cnt; i += 256) {
    unsigned e = stage[i];
    int bb = e >> 24;
    ebuf[bb * BSTRIDE + gbase[bb] + (i - lscan[bb])] = e;   // coalesced runs
  }
}

// ---------- K2: per-bucket counting sort, split by key half-range (R17) ----------
__global__ __launch_bounds__(256) void bucket_sort(
    const unsigned* __restrict__ ebuf, const unsigned* __restrict__ bcur,
    unsigned short* __restrict__ edge_src, int* __restrict__ row_start,
    int* __restrict__ deg) {
  __shared__ int lhist[128], lscan[128], lcur[128];
  __shared__ unsigned short srt[BSTRIDE / 2];    // 8 KB (half ~2048 +- 45)
  int B = blockIdx.x, t = threadIdx.x;
  int b = B >> 1, h = B & 1;
  int s0 = b * BSTRIDE;
  int cnt = (int)bcur[b];

  if (t < 128) lhist[t] = 0;
  __syncthreads();
  for (int i = t; i < cnt; i += 256) {
    int bin = (int)((ebuf[s0 + i] >> 16) & 255);
    if ((bin >> 7) == h) atomicAdd(&lhist[bin & 127], 1);
  }
  __syncthreads();

  int v = (t < 128) ? lhist[t] : 0;
  if (t < 128) lscan[t] = v;
  __syncthreads();
  for (int off = 1; off < 128; off <<= 1) {
    int a = (t >= off && t < 128) ? lscan[t - off] : 0;
    __syncthreads();
    if (t < 128) lscan[t] += a;
    __syncthreads();
  }
  if (t < 128) { lscan[t] -= v; lcur[t] = lscan[t]; }   // exclusive scan
  __syncthreads();

  int total = lscan[127] + lhist[127];   // edges in this half
  int base  = h ? (cnt - total) : 0;     // offset of this half within bucket

  for (int i = t; i < cnt; i += 256) {
    unsigned e = ebuf[s0 + i];
    int bin = (int)((e >> 16) & 255);
    if ((bin >> 7) == h) {
      int p = atomicAdd(&lcur[bin & 127], 1);
      srt[p] = (unsigned short)(e & 0xFFFFu);
    }
  }
  __syncthreads();

  for (int i = t; i < total; i += 256) edge_src[s0 + base + i] = srt[i];  // coalesced 2B

  if (t < 128) {
    int n = b * 256 + h * 128 + t;
    if (n < N_NODES) { row_start[n] = s0 + base + lscan[t]; deg[n] = v; }
  }
}

// ---------- fused layer: octet-per-node aggregate -> LDS -> MFMA linear ----------
// Block = 4 waves = 32 nodes = 2 MFMA tiles.
// Phase 1 (R18): software-pipelined gather. Old code had a per-edge
//   conditional chain edge_src -> feat16 -> acc that the compiler could not
//   pipeline across batches => ~1000 cyc serial latency per edge, ~16K cyc/wave.
//   New: unconditional 8-wide batches (edge index clamped to d-1), all 8 feat
//   loads in flight, NEXT batch's edge ids prefetched under the feat latency.
//   Accumulation order unchanged (masked adds only in tail) => bitwise-identical.
// Phase 2: MFMA linear; wave w does nt-half (w&1) of tile (w>>1).
__global__ __launch_bounds__(256) void sage_layer_fused(
    const half8*    __restrict__ feat16,    // [N,8] gather source (= self16)
    const _Float16* __restrict__ self16,    // [N,64]
    const int*      __restrict__ row_start,
    const int*      __restrict__ deg,
    const unsigned short* __restrict__ edge_src,
    const _Float16* __restrict__ Wt,        // [64,128]  Wt[n][k] = W[k][n]
    const float*    __restrict__ bias,      // [64]
    float*          __restrict__ outf,      // [N,64] f32 or null
    unsigned short* __restrict__ out16,     // [N,64] f16 or null
    int do_relu) {
  __shared__ _Float16 lmean[32 * 72];       // node stride 72 halves, 4.6 KB
  int t = threadIdx.x;
  int w = t >> 6, lane = t & 63;

  // ---- phase 1: aggregate 8 nodes per wave (octet-per-node, pipelined) ----
  {
    int o = lane >> 3, q = lane & 7;
    int n = blockIdx.x * 32 + w * 8 + o;
    if (n < N_NODES) {
      int start = row_start[n];
      int d     = deg[n];
      half8 acc8 = (half8){0, 0, 0, 0, 0, 0, 0, 0};
      if (d > 0) {
        int nb = (d + 7) >> 3;             // number of 8-batches
        int dm1 = d - 1;
        int sid[8];
        #pragma unroll
        for (int u = 0; u < 8; ++u) {
          int e = u > dm1 ? dm1 : u;       // clamp: unconditional load
          sid[u] = (int)edge_src[start + e];
        }
        for (int b = 0; b < nb; ++b) {
          half8 h[8];
          #pragma unroll
          for (int u = 0; u < 8; ++u)      // 8 independent 16B loads in flight
            h[u] = feat16[(size_t)sid[u] * 8 + q];
          int nsid[8];
          if (b + 1 < nb) {                // prefetch next batch's edge ids
            int nb0 = (b + 1) * 8;         // (hides edge_src->feat chain)
            #pragma unroll
            for (int u = 0; u < 8; ++u) {
              int e = nb0 + u; if (e > dm1) e = dm1;
              nsid[u] = (int)edge_src[start + e];
            }
          }
          int b0 = b * 8;
          if (b0 + 8 <= d) {               // full batch: unconditional adds
            #pragma unroll
            for (int u = 0; u < 8; ++u) acc8 += h[u];
          } else {                          // tail batch: masked adds (order kept)
            #pragma unroll
            for (int u = 0; u < 8; ++u) if (b0 + u < d) acc8 += h[u];
          }
          if (b + 1 < nb) {
            #pragma unroll
            for (int u = 0; u < 8; ++u) sid[u] = nsid[u];
          }
        }
      }
      float inv = (d > 0) ? 1.0f / (float)d : 0.0f;
      half8 hm;
      #pragma unroll
      for (int k = 0; k < 8; ++k) hm[k] = (_Float16)((float)acc8[k] * inv);
      *(half8*)&lmean[(w * 8 + o) * 72 + q * 8] = hm;
    }
  }
  __syncthreads();

  // ---- phase 2: MFMA linear; wave w does nt-half (w&1) of tile (w>>1) ----
  int tile = w >> 1;
  int wt = blockIdx.x * 2 + tile;
  if (wt >= NWTILE) return;
  int m = lane & 15, quad = lane >> 4;
  size_t arow = (size_t)(wt * 16 + m) * 64 + quad * 8;
  half8 a0 = *(const half8*)(self16 + arow);
  half8 a1 = *(const half8*)(self16 + arow + 32);
  int ln = tile * 16 + m;                   // local node 0..31
  half8 a2 = *(const half8*)&lmean[ln * 72 + quad * 8];
  half8 a3 = *(const half8*)&lmean[ln * 72 + quad * 8 + 32];

  int nt0 = (w & 1) * 2;                    // 0 or 2
  #pragma unroll
  for (int i = 0; i < 2; ++i) {
    int nt = nt0 + i;
    float bv = bias[nt * 16 + m];           // col = lane&15
    f32x4 acc = (f32x4){bv, bv, bv, bv};
    const _Float16* wrow = Wt + (size_t)(nt * 16 + m) * 128 + quad * 8;
    half8 b0 = *(const half8*)(wrow);
    half8 b1 = *(const half8*)(wrow + 32);
    half8 b2 = *(const half8*)(wrow + 64);
    half8 b3 = *(const half8*)(wrow + 96);
    acc = __builtin_amdgcn_mfma_f32_16x16x32_f16(a0, b0, acc, 0, 0, 0);
    acc = __builtin_amdgcn_mfma_f32_16x16x32_f16(a1, b1, acc, 0, 0, 0);
    acc = __builtin_amdgcn_mfma_f32_16x16x32_f16(a2, b2, acc, 0, 0, 0);
    acc = __builtin_amdgcn_mfma_f32_16x16x32_f16(a3, b3, acc, 0, 0, 0);
    #pragma unroll
    for (int r = 0; r < 4; ++r) {
      size_t off = (size_t)(wt * 16 + quad * 4 + r) * 64 + nt * 16 + m;
      float v = acc[r];
      if (do_relu) v = fmaxf(v, 0.0f);
      if (outf)  outf[off] = v;
      if (out16) { _Float16 hv = (_Float16)v; out16[off] = *(unsigned short*)&hv; }
    }
  }
}

extern "C" void kernel_launch(void* const* d_in, const int* in_sizes, int n_in,
                              void* d_out, int out_size, void* d_ws, size_t ws_size,
                              hipStream_t stream) {
  const float* x  = (const float*)d_in[0];
  const int*   ei = (const int*)d_in[1];   // [2,E]: row 0 = src, row 1 = dst
  const float* W1 = (const float*)d_in[2];
  const float* b1 = (const float*)d_in[3];
  const float* W2 = (const float*)d_in[4];
  const float* b2 = (const float*)d_in[5];
  float* out = (float*)d_out;

  const int* src = ei;
  const int* dst = ei + N_EDGES;

  // ws layout (int offsets), all 16B-aligned (R14 proven):
  //   bcur@0[256] | deg@256[50048] | row_start@50304[50048] |
  //   edge_src@100352[196*8192 ushorts = 802816 ints] | ebuf@903168[1605632] |
  //   x16@2508800[1600000] | h116@4108800[1600000] |
  //   Wt1@5708800[4096] | Wt2@5712896[4096]   total 5,716,992 ints = 22.9 MB
  int* wsi       = (int*)d_ws;
  unsigned* bcur = (unsigned*)wsi;
  int* deg       = wsi + 256;
  int* row_start = wsi + 50304;
  unsigned short* edge_src = (unsigned short*)(wsi + 100352);
  unsigned* ebuf = (unsigned*)(wsi + 903168);
  half8* x16     = (half8*)(wsi + 2508800);
  unsigned short* h116 = (unsigned short*)(wsi + 4108800);
  _Float16* Wt1  = (_Float16*)(wsi + 5708800);
  _Float16* Wt2  = (_Float16*)(wsi + 5712896);

  hipMemsetAsync(bcur, 0, 256 * sizeof(unsigned), stream);

  dim3 blk(256);
  partition_conv<<<NWG1 + 1, blk, 0, stream>>>(
      src, dst, (const float4*)x, x16, W1, W2, Wt1, Wt2, bcur, ebuf);
  bucket_sort<<<NBUCK * 2, blk, 0, stream>>>(ebuf, bcur, edge_src, row_start, deg);

  dim3 grd_fused((N_NODES + 31) / 32);   // 1563 blocks = 3126 tiles >= 3125

  // Layer 1: h1 = relu([x||mean]W1+b1), kept only as f16
  sage_layer_fused<<<grd_fused, blk, 0, stream>>>(
      x16, (const _Float16*)x16, row_start, deg, edge_src,
      Wt1, b1, nullptr, h116, 1);
  // Layer 2: out = [h1||mean]W2+b2 (f32)
  sage_layer_fused<<<grd_fused, blk, 0, stream>>>(
      (const half8*)h116, (const _Float16*)h116, row_start, deg, edge_src,
      Wt2, b2, out, nullptr, 0);
}